// Round 3
// baseline (523.931 us; speedup 1.0000x reference)
//
#include <hip/hip_runtime.h>
#include <math.h>

// ================= bucketed CSR build =================
// Buckets of 64 consecutive node ids; edges packed as (src<<6)|(dst&63).

__global__ void bucket_hist(const int* __restrict__ dst, int* __restrict__ bcnt,
                            int E, int nbucket) {
    extern __shared__ int h[];
    for (int i = threadIdx.x; i < nbucket; i += blockDim.x) h[i] = 0;
    __syncthreads();
    for (int e = blockIdx.x * blockDim.x + threadIdx.x; e < E; e += gridDim.x * blockDim.x)
        atomicAdd(&h[dst[e] >> 6], 1);
    __syncthreads();
    for (int i = threadIdx.x; i < nbucket; i += blockDim.x) {
        int v = h[i];
        if (v) atomicAdd(&bcnt[i], v);
    }
}

__global__ void bucket_scan(const int* __restrict__ bcnt, int* __restrict__ bbase,
                            int* __restrict__ cursor, int nbucket) {
    __shared__ int lds[256];
    __shared__ int carry;
    int t = threadIdx.x;
    if (t == 0) carry = 0;
    __syncthreads();
    for (int c = 0; c < nbucket; c += 256) {
        int v = (c + t < nbucket) ? bcnt[c + t] : 0;
        lds[t] = v;
        __syncthreads();
        for (int off = 1; off < 256; off <<= 1) {
            int y = (t >= off) ? lds[t - off] : 0;
            __syncthreads();
            lds[t] += y;
            __syncthreads();
        }
        if (c + t < nbucket) {
            int base = carry + lds[t] - v;
            bbase[c + t] = base;
            cursor[c + t] = base;
        }
        __syncthreads();
        if (t == 0) carry += lds[255];
        __syncthreads();
    }
    if (t == 0) bbase[nbucket] = carry;
}

__global__ void bucket_scatter(const int* __restrict__ src, const int* __restrict__ dst,
                               int* __restrict__ cursor, int* __restrict__ bucketed, int E) {
    for (int e = blockIdx.x * blockDim.x + threadIdx.x; e < E; e += gridDim.x * blockDim.x) {
        int s = src[e], d = dst[e];
        int pos = atomicAdd(&cursor[d >> 6], 1);
        bucketed[pos] = (s << 6) | (d & 63);
    }
}

// one block per bucket: per-node degree (LDS), local scan, grouped csr write,
// plus rowptr/rowend/dinv — all dense within the bucket's contiguous range.
__global__ void bucket_finalize(const int* __restrict__ bucketed, const int* __restrict__ bbase,
                                int* __restrict__ rowptr, int* __restrict__ rowend,
                                float* __restrict__ dinv, int* __restrict__ csr_src,
                                int n) {
    __shared__ int deg[64], excl[64], lcur[64];
    int b = blockIdx.x;
    int t = threadIdx.x;
    int base = bbase[b], bend = bbase[b + 1];
    int cnt = bend - base;
    if (t < 64) deg[t] = 0;
    __syncthreads();
    for (int i = t; i < cnt; i += blockDim.x)
        atomicAdd(&deg[bucketed[base + i] & 63], 1);
    __syncthreads();
    if (t == 0) {
        int run = 0;
        for (int i = 0; i < 64; ++i) { excl[i] = run; run += deg[i]; }
    }
    __syncthreads();
    if (t < 64) {
        lcur[t] = excl[t];
        int node = b * 64 + t;
        if (node < n) {
            int r = base + excl[t];
            rowptr[node] = r;
            rowend[node] = r + deg[t];
            dinv[node] = rsqrtf((float)(deg[t] + 1));
        }
    }
    __syncthreads();
    for (int i = t; i < cnt; i += blockDim.x) {
        int p = bucketed[base + i];
        int pos = atomicAdd(&lcur[p & 63], 1);
        csr_src[base + pos] = p >> 6;
    }
}

// ================= aggregation (gather, no atomics) =================
// out[d][j] = dinv[d]^2 * feat[d][j] + sum_k dinv[s_k]*dinv[d] * feat[s_k][j]

template <int D, int NPB>  // dims per row, nodes per block (D*NPB == 256)
__global__ void agg_gather(const int* __restrict__ rowptr, const int* __restrict__ rowend,
                           const int* __restrict__ csr_src, const float* __restrict__ dinv,
                           const float* __restrict__ feat, float* __restrict__ out, int n) {
    int node = blockIdx.x * NPB + (threadIdx.x / D);
    int j = threadIdx.x % D;
    if (node >= n) return;
    int k = rowptr[node];
    int end = rowend[node];
    float di = dinv[node];
    float acc = feat[(size_t)node * D + j] * di * di;
    for (; k + 4 <= end; k += 4) {
        int s0 = csr_src[k], s1 = csr_src[k + 1], s2 = csr_src[k + 2], s3 = csr_src[k + 3];
        float w0 = dinv[s0] * di, w1 = dinv[s1] * di, w2 = dinv[s2] * di, w3 = dinv[s3] * di;
        float v0 = feat[(size_t)s0 * D + j];
        float v1 = feat[(size_t)s1 * D + j];
        float v2 = feat[(size_t)s2 * D + j];
        float v3 = feat[(size_t)s3 * D + j];
        acc += v0 * w0 + v1 * w1 + v2 * w2 + v3 * w3;
    }
    for (; k < end; ++k) {
        int s = csr_src[k];
        acc += feat[(size_t)s * D + j] * dinv[s] * di;
    }
    out[(size_t)node * D + j] = acc;
}

// ================= dense layers =================

template <int K>
__global__ void gemm_bias_relu(const float* __restrict__ in, const float* __restrict__ W,
                               const float* __restrict__ bias, float* __restrict__ out, int n) {
    __shared__ float Ws[K * 64];
    __shared__ float bs[64];
    int t = threadIdx.x;
    for (int i = t; i < K * 64; i += 256) Ws[i] = W[i];
    if (t < 64) bs[t] = bias[t];
    __syncthreads();
    int row = blockIdx.x * 4 + (t >> 6);
    int j = t & 63;
    if (row >= n) return;
    const float* xr = in + (size_t)row * K;
    float acc = bs[j];
#pragma unroll
    for (int k = 0; k < K; ++k) acc += xr[k] * Ws[k * 64 + j];
    out[(size_t)row * 64 + j] = fmaxf(acc, 0.0f);
}

// fused: h2 = relu(in@W2 + b2); g[j] += column sums of h2 (h2 never stored)
__global__ void gemm_relu_pool(const float* __restrict__ in, const float* __restrict__ W,
                               const float* __restrict__ bias, float* __restrict__ g, int n) {
    __shared__ float Ws[64 * 64];
    int t = threadIdx.x;
    for (int i = t; i < 64 * 64; i += 256) Ws[i] = W[i];
    __syncthreads();
    int j = t & 63;
    float b = bias[j];
    float pool = 0.0f;
    for (int row = blockIdx.x * 4 + (t >> 6); row < n; row += gridDim.x * 4) {
        const float* xr = in + (size_t)row * 64;
        float acc = b;
#pragma unroll
        for (int k = 0; k < 64; ++k) acc += xr[k] * Ws[k * 64 + j];
        pool += fmaxf(acc, 0.0f);
    }
    __shared__ float sd[256];
    sd[t] = pool;
    __syncthreads();
    if (t < 64) atomicAdd(&g[t], sd[t] + sd[t + 64] + sd[t + 128] + sd[t + 192]);
}

__global__ void final_head(const float* __restrict__ g, const float* __restrict__ Wfc,
                           const float* __restrict__ bfc, float* __restrict__ out, int n) {
    __shared__ float logits[5];
    int t = threadIdx.x;
    if (t < 5) {
        float acc = bfc[t];
        float invn = 1.0f / (float)n;
        for (int k = 0; k < 64; ++k) acc += (g[k] * invn) * Wfc[k * 5 + t];
        logits[t] = acc;
    }
    __syncthreads();
    if (t == 0) {
        float m = logits[0];
        for (int i = 1; i < 5; ++i) m = fmaxf(m, logits[i]);
        float s = 0.0f;
        for (int i = 0; i < 5; ++i) s += expf(logits[i] - m);
        float lse = m + logf(s);
        for (int i = 0; i < 5; ++i) out[i] = logits[i] - lse;
    }
}

// ================= launch =================

extern "C" void kernel_launch(void* const* d_in, const int* in_sizes, int n_in,
                              void* d_out, int out_size, void* d_ws, size_t ws_size,
                              hipStream_t stream) {
    const float* x   = (const float*)d_in[0];
    const int*   ei  = (const int*)d_in[1];
    const float* W1  = (const float*)d_in[2];
    const float* b1  = (const float*)d_in[3];
    const float* W2  = (const float*)d_in[4];
    const float* b2  = (const float*)d_in[5];
    const float* Wfc = (const float*)d_in[6];
    const float* bfc = (const float*)d_in[7];
    float* out = (float*)d_out;

    const int n = in_sizes[0] / 32;   // 100000
    const int E = in_sizes[1] / 2;    // 1600000
    const int* src = ei;
    const int* dst = ei + E;
    const int nbucket = (n + 63) >> 6;

    // workspace carve-up (4-byte units)
    int*   csr_src = (int*)d_ws;                       // [E] (persists)
    int*   rowptr  = csr_src + E;                      // [n]
    int*   rowend  = rowptr + n;                       // [n]
    float* dinv    = (float*)(rowend + n);             // [n]
    int*   bcnt    = (int*)(dinv + n);                 // [nbucket]
    int*   bbase   = bcnt + nbucket;                   // [nbucket+1]
    int*   cursor  = bbase + nbucket + 1;              // [nbucket]
    size_t ofs     = (size_t)E + 3 * (size_t)n + 3 * (size_t)nbucket + 1;
    ofs            = (ofs + 3) & ~(size_t)3;           // 16B align
    float* aggbuf  = (float*)d_ws + ofs;               // [n*64]
    float* h1      = aggbuf + (size_t)n * 64;          // [n*64]
    float* g       = h1 + (size_t)n * 64;              // [64]
    int*   bucketed = (int*)h1;                        // alias: [E] used before h1 written

    const int B = 256;

    // ---- build CSR + norms ----
    hipMemsetAsync(bcnt, 0, (size_t)nbucket * sizeof(int), stream);
    bucket_hist<<<256, B, nbucket * sizeof(int), stream>>>(dst, bcnt, E, nbucket);
    bucket_scan<<<1, B, 0, stream>>>(bcnt, bbase, cursor, nbucket);
    bucket_scatter<<<1024, B, 0, stream>>>(src, dst, cursor, bucketed, E);
    bucket_finalize<<<nbucket, B, 0, stream>>>(bucketed, bbase, rowptr, rowend, dinv, csr_src, n);

    // ---- layer 1: agg(x) [n,32] then gemm+bias+relu -> h1 [n,64] ----
    agg_gather<32, 8><<<(n + 7) / 8, B, 0, stream>>>(rowptr, rowend, csr_src, dinv, x, aggbuf, n);
    gemm_bias_relu<32><<<(n + 3) / 4, B, 0, stream>>>(aggbuf, W1, b1, h1, n);

    // ---- layer 2: agg(h1) [n,64] then fused gemm+relu+pool ----
    agg_gather<64, 4><<<(n + 3) / 4, B, 0, stream>>>(rowptr, rowend, csr_src, dinv, h1, aggbuf, n);
    hipMemsetAsync(g, 0, 64 * sizeof(float), stream);
    gemm_relu_pool<<<1024, B, 0, stream>>>(aggbuf, W2, b2, g, n);

    // ---- head ----
    final_head<<<1, 64, 0, stream>>>(g, Wfc, bfc, out, n);
}

// Round 4
// 362.395 us; speedup vs baseline: 1.4457x; 1.4457x over previous
//
#include <hip/hip_runtime.h>
#include <math.h>

#define NBLK 128  // number of chunks/blocks for hist+scatter (must match both)

// ================= deterministic bucketed CSR build =================
// Bucket = 256 consecutive node ids (dst>>8). Edge packed as (src<<8)|(dst&255).
// src < 2^17, so packed fits in 25 bits.

__global__ void pass_hist(const int* __restrict__ dst, int* __restrict__ cnt,
                          int E, int nbucket, int chunk) {
    extern __shared__ int h[];
    int blk = blockIdx.x;
    for (int i = threadIdx.x; i < nbucket; i += blockDim.x) h[i] = 0;
    __syncthreads();
    int lo = blk * chunk, hi = min(lo + chunk, E);
    for (int e = lo + threadIdx.x; e < hi; e += blockDim.x)
        atomicAdd(&h[dst[e] >> 8], 1);
    __syncthreads();
    for (int i = threadIdx.x; i < nbucket; i += blockDim.x)
        cnt[i * NBLK + blk] = h[i];  // bucket-major, block-minor
}

// in-place exclusive scan of a[0..M); a[M] = total. single block, 256 thr x 4.
__global__ void scan_flat(int* __restrict__ a, int M) {
    __shared__ int lds[256];
    __shared__ int carry;
    int t = threadIdx.x;
    if (t == 0) carry = 0;
    __syncthreads();
    for (int c = 0; c < M; c += 1024) {
        int base = c + t * 4;
        int v0 = (base + 0 < M) ? a[base + 0] : 0;
        int v1 = (base + 1 < M) ? a[base + 1] : 0;
        int v2 = (base + 2 < M) ? a[base + 2] : 0;
        int v3 = (base + 3 < M) ? a[base + 3] : 0;
        int s = v0 + v1 + v2 + v3;
        lds[t] = s;
        __syncthreads();
        for (int off = 1; off < 256; off <<= 1) {
            int y = (t >= off) ? lds[t - off] : 0;
            __syncthreads();
            lds[t] += y;
            __syncthreads();
        }
        int eb = carry + lds[t] - s;
        if (base + 0 < M) a[base + 0] = eb;
        if (base + 1 < M) a[base + 1] = eb + v0;
        if (base + 2 < M) a[base + 2] = eb + v0 + v1;
        if (base + 3 < M) a[base + 3] = eb + v0 + v1 + v2;
        __syncthreads();
        if (t == 0) carry += lds[255];
        __syncthreads();
    }
    if (t == 0) a[M] = carry;
}

__global__ void pass_scatter(const int* __restrict__ src, const int* __restrict__ dst,
                             const int* __restrict__ ofs, int* __restrict__ bucketed,
                             int E, int nbucket, int chunk) {
    extern __shared__ int lcur[];
    int blk = blockIdx.x;
    for (int i = threadIdx.x; i < nbucket; i += blockDim.x)
        lcur[i] = ofs[i * NBLK + blk];
    __syncthreads();
    int lo = blk * chunk, hi = min(lo + chunk, E);
    for (int e = lo + threadIdx.x; e < hi; e += blockDim.x) {
        int s = src[e], d = dst[e];
        int pos = atomicAdd(&lcur[d >> 8], 1);
        bucketed[pos] = (s << 8) | (d & 255);
    }
}

// one block per 256-node bucket: LDS degree count, scan, regroup to CSR,
// write rowptr/rowend/dinv — all dense within the bucket's contiguous range.
__global__ void bucket_finalize(const int* __restrict__ bucketed, const int* __restrict__ ofs,
                                int* __restrict__ rowptr, int* __restrict__ rowend,
                                float* __restrict__ dinv, int* __restrict__ csr_src, int n) {
    __shared__ int deg[256], sc[256], lcur[256];
    int b = blockIdx.x, t = threadIdx.x;
    int base = ofs[b * NBLK];
    int bend = ofs[(b + 1) * NBLK];  // sentinel covers last bucket
    deg[t] = 0;
    __syncthreads();
    for (int i = base + t; i < bend; i += 256)
        atomicAdd(&deg[bucketed[i] & 255], 1);
    __syncthreads();
    int v = deg[t];
    sc[t] = v;
    __syncthreads();
    for (int off = 1; off < 256; off <<= 1) {
        int y = (t >= off) ? sc[t - off] : 0;
        __syncthreads();
        sc[t] += y;
        __syncthreads();
    }
    int ex = sc[t] - v;  // exclusive within-bucket offset
    lcur[t] = ex;
    int node = b * 256 + t;
    if (node < n) {
        rowptr[node] = base + ex;
        rowend[node] = base + ex + v;
        dinv[node] = rsqrtf((float)(v + 1));
    }
    __syncthreads();
    for (int i = base + t; i < bend; i += 256) {
        int p = bucketed[i];
        int pos = atomicAdd(&lcur[p & 255], 1);
        csr_src[base + pos] = p >> 8;
    }
}

// ================= aggregation (gather, no atomics) =================
// out[d][j] = dinv[d]^2 * feat[d][j] + sum_k dinv[s_k]*dinv[d] * feat[s_k][j]

template <int D, int NPB>  // dims per row, nodes per block (D*NPB == 256)
__global__ void agg_gather(const int* __restrict__ rowptr, const int* __restrict__ rowend,
                           const int* __restrict__ csr_src, const float* __restrict__ dinv,
                           const float* __restrict__ feat, float* __restrict__ out, int n) {
    int node = blockIdx.x * NPB + (threadIdx.x / D);
    int j = threadIdx.x % D;
    if (node >= n) return;
    int k = rowptr[node];
    int end = rowend[node];
    float di = dinv[node];
    float acc = feat[(size_t)node * D + j] * di * di;
    for (; k + 4 <= end; k += 4) {
        int s0 = csr_src[k], s1 = csr_src[k + 1], s2 = csr_src[k + 2], s3 = csr_src[k + 3];
        float w0 = dinv[s0] * di, w1 = dinv[s1] * di, w2 = dinv[s2] * di, w3 = dinv[s3] * di;
        float v0 = feat[(size_t)s0 * D + j];
        float v1 = feat[(size_t)s1 * D + j];
        float v2 = feat[(size_t)s2 * D + j];
        float v3 = feat[(size_t)s3 * D + j];
        acc += v0 * w0 + v1 * w1 + v2 * w2 + v3 * w3;
    }
    for (; k < end; ++k) {
        int s = csr_src[k];
        acc += feat[(size_t)s * D + j] * dinv[s] * di;
    }
    out[(size_t)node * D + j] = acc;
}

// ================= dense layers =================

template <int K>
__global__ void gemm_bias_relu(const float* __restrict__ in, const float* __restrict__ W,
                               const float* __restrict__ bias, float* __restrict__ out, int n) {
    __shared__ float Ws[K * 64];
    __shared__ float bs[64];
    int t = threadIdx.x;
    for (int i = t; i < K * 64; i += 256) Ws[i] = W[i];
    if (t < 64) bs[t] = bias[t];
    __syncthreads();
    int row = blockIdx.x * 4 + (t >> 6);
    int j = t & 63;
    if (row >= n) return;
    const float* xr = in + (size_t)row * K;
    float acc = bs[j];
#pragma unroll
    for (int k = 0; k < K; ++k) acc += xr[k] * Ws[k * 64 + j];
    out[(size_t)row * 64 + j] = fmaxf(acc, 0.0f);
}

// fused: h2 = relu(in@W2 + b2); g[j] += column sums of h2 (h2 never stored)
__global__ void gemm_relu_pool(const float* __restrict__ in, const float* __restrict__ W,
                               const float* __restrict__ bias, float* __restrict__ g, int n) {
    __shared__ float Ws[64 * 64];
    int t = threadIdx.x;
    for (int i = t; i < 64 * 64; i += 256) Ws[i] = W[i];
    __syncthreads();
    int j = t & 63;
    float b = bias[j];
    float pool = 0.0f;
    for (int row = blockIdx.x * 4 + (t >> 6); row < n; row += gridDim.x * 4) {
        const float* xr = in + (size_t)row * 64;
        float acc = b;
#pragma unroll
        for (int k = 0; k < 64; ++k) acc += xr[k] * Ws[k * 64 + j];
        pool += fmaxf(acc, 0.0f);
    }
    __shared__ float sd[256];
    sd[t] = pool;
    __syncthreads();
    if (t < 64) atomicAdd(&g[t], sd[t] + sd[t + 64] + sd[t + 128] + sd[t + 192]);
}

__global__ void final_head(const float* __restrict__ g, const float* __restrict__ Wfc,
                           const float* __restrict__ bfc, float* __restrict__ out, int n) {
    __shared__ float logits[5];
    int t = threadIdx.x;
    if (t < 5) {
        float acc = bfc[t];
        float invn = 1.0f / (float)n;
        for (int k = 0; k < 64; ++k) acc += (g[k] * invn) * Wfc[k * 5 + t];
        logits[t] = acc;
    }
    __syncthreads();
    if (t == 0) {
        float m = logits[0];
        for (int i = 1; i < 5; ++i) m = fmaxf(m, logits[i]);
        float s = 0.0f;
        for (int i = 0; i < 5; ++i) s += expf(logits[i] - m);
        float lse = m + logf(s);
        for (int i = 0; i < 5; ++i) out[i] = logits[i] - lse;
    }
}

// ================= launch =================

extern "C" void kernel_launch(void* const* d_in, const int* in_sizes, int n_in,
                              void* d_out, int out_size, void* d_ws, size_t ws_size,
                              hipStream_t stream) {
    const float* x   = (const float*)d_in[0];
    const int*   ei  = (const int*)d_in[1];
    const float* W1  = (const float*)d_in[2];
    const float* b1  = (const float*)d_in[3];
    const float* W2  = (const float*)d_in[4];
    const float* b2  = (const float*)d_in[5];
    const float* Wfc = (const float*)d_in[6];
    const float* bfc = (const float*)d_in[7];
    float* out = (float*)d_out;

    const int n = in_sizes[0] / 32;   // 100000
    const int E = in_sizes[1] / 2;    // 1600000
    const int* src = ei;
    const int* dst = ei + E;
    const int nbucket = (n + 255) >> 8;              // 256-node buckets
    const int chunk = (E + NBLK - 1) / NBLK;
    const int M = nbucket * NBLK;                    // count-matrix size

    // workspace carve-up (4-byte units)
    int*   csr_src = (int*)d_ws;                     // [E]
    int*   rowptr  = csr_src + E;                    // [n]
    int*   rowend  = rowptr + n;                     // [n]
    float* dinv    = (float*)(rowend + n);           // [n]
    int*   cnt     = (int*)(dinv + n);               // [M+1] -> scanned offsets
    size_t ofs     = (size_t)E + 3 * (size_t)n + (size_t)M + 1;
    ofs            = (ofs + 3) & ~(size_t)3;         // 16B align
    float* aggbuf  = (float*)d_ws + ofs;             // [n*64]
    float* h1      = aggbuf + (size_t)n * 64;        // [n*64]
    float* g       = h1 + (size_t)n * 64;            // [64]
    int*   bucketed = (int*)h1;                      // alias: [E] consumed before h1 written

    const int B = 256;
    const size_t lds_b = (size_t)nbucket * sizeof(int);

    // ---- build CSR + norms (no global atomics) ----
    pass_hist<<<NBLK, B, lds_b, stream>>>(dst, cnt, E, nbucket, chunk);
    scan_flat<<<1, B, 0, stream>>>(cnt, M);
    pass_scatter<<<NBLK, B, lds_b, stream>>>(src, dst, cnt, bucketed, E, nbucket, chunk);
    bucket_finalize<<<nbucket, B, 0, stream>>>(bucketed, cnt, rowptr, rowend, dinv, csr_src, n);

    // ---- layer 1: agg(x) [n,32] then gemm+bias+relu -> h1 [n,64] ----
    agg_gather<32, 8><<<(n + 7) / 8, B, 0, stream>>>(rowptr, rowend, csr_src, dinv, x, aggbuf, n);
    gemm_bias_relu<32><<<(n + 3) / 4, B, 0, stream>>>(aggbuf, W1, b1, h1, n);

    // ---- layer 2: agg(h1) [n,64] then fused gemm+relu+pool ----
    agg_gather<64, 4><<<(n + 3) / 4, B, 0, stream>>>(rowptr, rowend, csr_src, dinv, h1, aggbuf, n);
    hipMemsetAsync(g, 0, 64 * sizeof(float), stream);
    gemm_relu_pool<<<1024, B, 0, stream>>>(aggbuf, W2, b2, g, n);

    // ---- head ----
    final_head<<<1, 64, 0, stream>>>(g, Wfc, bfc, out, n);
}

// Round 5
// 249.364 us; speedup vs baseline: 2.1011x; 1.4533x over previous
//
#include <hip/hip_runtime.h>
#include <math.h>

#define NBLK 256  // chunks/blocks for hist+scatter

typedef unsigned int uint;

__device__ __forceinline__ uint pack_bf16(float a, float b) {
    uint ua = __float_as_uint(a), ub = __float_as_uint(b);
    ua = (ua + 0x7fffu + ((ua >> 16) & 1u)) >> 16;
    ub = (ub + 0x7fffu + ((ub >> 16) & 1u)) >> 16;
    return ua | (ub << 16);
}
__device__ __forceinline__ float bf_lo(uint w) { return __uint_as_float(w << 16); }
__device__ __forceinline__ float bf_hi(uint w) { return __uint_as_float(w & 0xffff0000u); }

// ================= deterministic bucketed CSR build =================
// Bucket = 256 consecutive node ids (dst>>8). Edge packed as (src<<8)|(dst&255).

__global__ void pass_hist(const int* __restrict__ dst, int* __restrict__ cnt,
                          int E, int nbucket, int chunk) {
    extern __shared__ int h[];
    int blk = blockIdx.x;
    for (int i = threadIdx.x; i < nbucket; i += blockDim.x) h[i] = 0;
    __syncthreads();
    int lo = blk * chunk, hi = min(lo + chunk, E);
    for (int e = lo + threadIdx.x; e < hi; e += blockDim.x)
        atomicAdd(&h[dst[e] >> 8], 1);
    __syncthreads();
    for (int i = threadIdx.x; i < nbucket; i += blockDim.x)
        cnt[i * NBLK + blk] = h[i];  // bucket-major, block-minor
}

// per-bucket exclusive scan of its NBLK counts; emits bucket total
__global__ void row_scan(int* __restrict__ cnt, int* __restrict__ totals) {
    __shared__ int lds[NBLK];
    int b = blockIdx.x, t = threadIdx.x;
    int v = cnt[b * NBLK + t];
    lds[t] = v;
    __syncthreads();
    for (int off = 1; off < NBLK; off <<= 1) {
        int y = (t >= off) ? lds[t - off] : 0;
        __syncthreads();
        lds[t] += y;
        __syncthreads();
    }
    cnt[b * NBLK + t] = lds[t] - v;
    if (t == NBLK - 1) totals[b] = lds[NBLK - 1];
}

// exclusive scan of totals[0..nb); totals[nb] = grand total. single block.
__global__ void total_scan(int* __restrict__ totals, int nb) {
    __shared__ int lds[256];
    __shared__ int carry;
    int t = threadIdx.x;
    if (t == 0) carry = 0;
    __syncthreads();
    for (int c = 0; c < nb; c += 256) {
        int v = (c + t < nb) ? totals[c + t] : 0;
        lds[t] = v;
        __syncthreads();
        for (int off = 1; off < 256; off <<= 1) {
            int y = (t >= off) ? lds[t - off] : 0;
            __syncthreads();
            lds[t] += y;
            __syncthreads();
        }
        if (c + t < nb) totals[c + t] = carry + lds[t] - v;
        __syncthreads();
        if (t == 0) carry += lds[255];
        __syncthreads();
    }
    if (t == 0) totals[nb] = carry;
}

__global__ void pass_scatter(const int* __restrict__ src, const int* __restrict__ dst,
                             const int* __restrict__ cnt, const int* __restrict__ totals,
                             int* __restrict__ bucketed, int E, int nbucket, int chunk) {
    extern __shared__ int lcur[];
    int blk = blockIdx.x;
    for (int i = threadIdx.x; i < nbucket; i += blockDim.x)
        lcur[i] = cnt[i * NBLK + blk] + totals[i];
    __syncthreads();
    int lo = blk * chunk, hi = min(lo + chunk, E);
    for (int e = lo + threadIdx.x; e < hi; e += blockDim.x) {
        int s = src[e], d = dst[e];
        int pos = atomicAdd(&lcur[d >> 8], 1);
        bucketed[pos] = (s << 8) | (d & 255);
    }
}

// one block per 256-node bucket: LDS degree count, scan, regroup to CSR,
// write rowptr/rowend/dinv — dense within the bucket's contiguous range.
__global__ void bucket_finalize(const int* __restrict__ bucketed, const int* __restrict__ totals,
                                int* __restrict__ rowptr, int* __restrict__ rowend,
                                float* __restrict__ dinv, int* __restrict__ csr_src, int n) {
    __shared__ int deg[256], sc[256], lcur[256];
    int b = blockIdx.x, t = threadIdx.x;
    int base = totals[b], bend = totals[b + 1];
    deg[t] = 0;
    __syncthreads();
    for (int i = base + t; i < bend; i += 256)
        atomicAdd(&deg[bucketed[i] & 255], 1);
    __syncthreads();
    int v = deg[t];
    sc[t] = v;
    __syncthreads();
    for (int off = 1; off < 256; off <<= 1) {
        int y = (t >= off) ? sc[t - off] : 0;
        __syncthreads();
        sc[t] += y;
        __syncthreads();
    }
    int ex = sc[t] - v;
    lcur[t] = ex;
    int node = b * 256 + t;
    if (node < n) {
        rowptr[node] = base + ex;
        rowend[node] = base + ex + v;
        dinv[node] = rsqrtf((float)(v + 1));
    }
    __syncthreads();
    for (int i = base + t; i < bend; i += 256) {
        int p = bucketed[i];
        int pos = atomicAdd(&lcur[p & 255], 1);
        csr_src[base + pos] = p >> 8;
    }
}

// ================= feature conversion =================

// pack fp32 [rows, 2*DW] into bf16-pair words [rows, DW]
__global__ void to_bf16_words(const float* __restrict__ in, uint* __restrict__ outw,
                              long long nwords) {
    long long i = (long long)blockIdx.x * blockDim.x + threadIdx.x;
    if (i < nwords) {
        float2 v = reinterpret_cast<const float2*>(in)[i];
        outw[i] = pack_bf16(v.x, v.y);
    }
}

// ================= aggregation (gather, no atomics, bf16 operand) =================
// out[d][2j+{0,1}] = dinv[d]^2*feat[d][..] + sum_k dinv[s_k]*dinv[d]*feat[s_k][..]

template <int DW, int NPB>  // words per row; nodes per 256-thread block = 256/DW
__global__ void agg_gather_bf16(const int* __restrict__ rowptr, const int* __restrict__ rowend,
                                const int* __restrict__ csr_src, const float* __restrict__ dinv,
                                const uint* __restrict__ feat, float* __restrict__ out, int n) {
    int node = blockIdx.x * NPB + (threadIdx.x / DW);
    int j = threadIdx.x % DW;
    if (node >= n) return;
    int k = rowptr[node];
    int end = rowend[node];
    float di = dinv[node];
    uint w = feat[(size_t)node * DW + j];
    float a0 = bf_lo(w) * di * di;
    float a1 = bf_hi(w) * di * di;
    for (; k + 4 <= end; k += 4) {
        int s0 = csr_src[k], s1 = csr_src[k + 1], s2 = csr_src[k + 2], s3 = csr_src[k + 3];
        float w0 = dinv[s0] * di, w1 = dinv[s1] * di, w2 = dinv[s2] * di, w3 = dinv[s3] * di;
        uint u0 = feat[(size_t)s0 * DW + j];
        uint u1 = feat[(size_t)s1 * DW + j];
        uint u2 = feat[(size_t)s2 * DW + j];
        uint u3 = feat[(size_t)s3 * DW + j];
        a0 += bf_lo(u0) * w0 + bf_lo(u1) * w1 + bf_lo(u2) * w2 + bf_lo(u3) * w3;
        a1 += bf_hi(u0) * w0 + bf_hi(u1) * w1 + bf_hi(u2) * w2 + bf_hi(u3) * w3;
    }
    for (; k < end; ++k) {
        int s = csr_src[k];
        float ws = dinv[s] * di;
        uint u = feat[(size_t)s * DW + j];
        a0 += bf_lo(u) * ws;
        a1 += bf_hi(u) * ws;
    }
    reinterpret_cast<float2*>(out + (size_t)node * 2 * DW)[j] = make_float2(a0, a1);
}

// ================= dense layers =================

// out_words[row][j/2] = bf16pack(relu(bias + in@W)), J=64. One wave per row.
template <int K>
__global__ void gemm_bias_relu_bf16(const float* __restrict__ in, const float* __restrict__ W,
                                    const float* __restrict__ bias, uint* __restrict__ outw,
                                    int n) {
    __shared__ float Ws[K * 64];
    __shared__ float bs[64];
    int t = threadIdx.x;
    for (int i = t; i < K * 64; i += 256) Ws[i] = W[i];
    if (t < 64) bs[t] = bias[t];
    __syncthreads();
    int row = blockIdx.x * 4 + (t >> 6);
    int j = t & 63;
    if (row >= n) return;
    const float* xr = in + (size_t)row * K;
    float acc = bs[j];
#pragma unroll
    for (int k = 0; k < K; ++k) acc += xr[k] * Ws[k * 64 + j];
    float o = fmaxf(acc, 0.0f);
    float other = __shfl_xor(o, 1);
    if ((j & 1) == 0) outw[(size_t)row * 32 + (j >> 1)] = pack_bf16(o, other);
}

// fused: h2 = relu(in@W2 + b2); g[j] += column sums of h2 (h2 never stored)
__global__ void gemm_relu_pool(const float* __restrict__ in, const float* __restrict__ W,
                               const float* __restrict__ bias, float* __restrict__ g, int n) {
    __shared__ float Ws[64 * 64];
    int t = threadIdx.x;
    for (int i = t; i < 64 * 64; i += 256) Ws[i] = W[i];
    __syncthreads();
    int j = t & 63;
    float b = bias[j];
    float pool = 0.0f;
    for (int row = blockIdx.x * 4 + (t >> 6); row < n; row += gridDim.x * 4) {
        const float* xr = in + (size_t)row * 64;
        float acc = b;
#pragma unroll
        for (int k = 0; k < 64; ++k) acc += xr[k] * Ws[k * 64 + j];
        pool += fmaxf(acc, 0.0f);
    }
    __shared__ float sd[256];
    sd[t] = pool;
    __syncthreads();
    if (t < 64) atomicAdd(&g[t], sd[t] + sd[t + 64] + sd[t + 128] + sd[t + 192]);
}

__global__ void final_head(const float* __restrict__ g, const float* __restrict__ Wfc,
                           const float* __restrict__ bfc, float* __restrict__ out, int n) {
    __shared__ float logits[5];
    int t = threadIdx.x;
    if (t < 5) {
        float acc = bfc[t];
        float invn = 1.0f / (float)n;
        for (int k = 0; k < 64; ++k) acc += (g[k] * invn) * Wfc[k * 5 + t];
        logits[t] = acc;
    }
    __syncthreads();
    if (t == 0) {
        float m = logits[0];
        for (int i = 1; i < 5; ++i) m = fmaxf(m, logits[i]);
        float s = 0.0f;
        for (int i = 0; i < 5; ++i) s += expf(logits[i] - m);
        float lse = m + logf(s);
        for (int i = 0; i < 5; ++i) out[i] = logits[i] - lse;
    }
}

// ================= launch =================

extern "C" void kernel_launch(void* const* d_in, const int* in_sizes, int n_in,
                              void* d_out, int out_size, void* d_ws, size_t ws_size,
                              hipStream_t stream) {
    const float* x   = (const float*)d_in[0];
    const int*   ei  = (const int*)d_in[1];
    const float* W1  = (const float*)d_in[2];
    const float* b1  = (const float*)d_in[3];
    const float* W2  = (const float*)d_in[4];
    const float* b2  = (const float*)d_in[5];
    const float* Wfc = (const float*)d_in[6];
    const float* bfc = (const float*)d_in[7];
    float* out = (float*)d_out;

    const int n = in_sizes[0] / 32;   // 100000
    const int E = in_sizes[1] / 2;    // 1600000
    const int* src = ei;
    const int* dst = ei + E;
    const int nbucket = (n + 255) >> 8;              // 256-node buckets
    const int chunk = (E + NBLK - 1) / NBLK;

    // workspace carve-up (4-byte units)
    int*   csr_src = (int*)d_ws;                     // [E]
    int*   rowptr  = csr_src + E;                    // [n]
    int*   rowend  = rowptr + n;                     // [n]
    float* dinv    = (float*)(rowend + n);           // [n]
    int*   cnt     = (int*)(dinv + n);               // [nbucket*NBLK]
    int*   totals  = cnt + (size_t)nbucket * NBLK;   // [nbucket+1]
    uint*  xbf     = (uint*)(totals + nbucket + 1);  // [n*16]
    uint*  h1bf    = xbf + (size_t)n * 16;           // [n*32]
    size_t ofs     = ((size_t)(h1bf + (size_t)n * 32 - (uint*)d_ws) + 3) & ~(size_t)3;
    float* aggbuf  = (float*)d_ws + ofs;             // [n*64]
    float* g       = aggbuf + (size_t)n * 64;        // [64]
    int*   bucketed = (int*)aggbuf;                  // alias: [E] consumed before aggbuf written

    const int B = 256;
    const size_t lds_b = (size_t)nbucket * sizeof(int);

    // ---- build CSR + norms (no global atomics) ----
    pass_hist<<<NBLK, B, lds_b, stream>>>(dst, cnt, E, nbucket, chunk);
    row_scan<<<nbucket, NBLK, 0, stream>>>(cnt, totals);
    total_scan<<<1, B, 0, stream>>>(totals, nbucket);
    pass_scatter<<<NBLK, B, lds_b, stream>>>(src, dst, cnt, totals, bucketed, E, nbucket, chunk);
    bucket_finalize<<<nbucket, B, 0, stream>>>(bucketed, totals, rowptr, rowend, dinv, csr_src, n);

    // ---- x -> bf16 words ----
    {
        long long nwords = (long long)n * 16;
        to_bf16_words<<<(int)((nwords + B - 1) / B), B, 0, stream>>>(x, xbf, nwords);
    }

    // ---- layer 1: agg(xbf) [n,32] fp32, then gemm+bias+relu -> h1bf [n,32w] ----
    agg_gather_bf16<16, 16><<<(n + 15) / 16, B, 0, stream>>>(rowptr, rowend, csr_src, dinv,
                                                             xbf, aggbuf, n);
    gemm_bias_relu_bf16<32><<<(n + 3) / 4, B, 0, stream>>>(aggbuf, W1, b1, h1bf, n);

    // ---- layer 2: agg(h1bf) [n,64] fp32, then fused gemm+relu+pool ----
    agg_gather_bf16<32, 8><<<(n + 7) / 8, B, 0, stream>>>(rowptr, rowend, csr_src, dinv,
                                                          h1bf, aggbuf, n);
    hipMemsetAsync(g, 0, 64 * sizeof(float), stream);
    gemm_relu_pool<<<1024, B, 0, stream>>>(aggbuf, W2, b2, g, n);

    // ---- head ----
    final_head<<<1, 64, 0, stream>>>(g, Wfc, bfc, out, n);
}

// Round 6
// 186.082 us; speedup vs baseline: 2.8156x; 1.3401x over previous
//
#include <hip/hip_runtime.h>
#include <math.h>

#define NBLK 256  // chunks/blocks for hist+scatter

typedef unsigned int uint;
typedef __attribute__((ext_vector_type(8))) short short8;
typedef __attribute__((ext_vector_type(4))) float f32x4;

__device__ __forceinline__ uint pack_bf16(float a, float b) {
    uint ua = __float_as_uint(a), ub = __float_as_uint(b);
    ua = (ua + 0x7fffu + ((ua >> 16) & 1u)) >> 16;
    ub = (ub + 0x7fffu + ((ub >> 16) & 1u)) >> 16;
    return ua | (ub << 16);
}
__device__ __forceinline__ float bf_lo(uint w) { return __uint_as_float(w << 16); }
__device__ __forceinline__ float bf_hi(uint w) { return __uint_as_float(w & 0xffff0000u); }

// ================= deterministic bucketed CSR build =================

__global__ void pass_hist(const int* __restrict__ dst, int* __restrict__ cnt,
                          int E, int nbucket, int chunk) {
    extern __shared__ int h[];
    int blk = blockIdx.x;
    for (int i = threadIdx.x; i < nbucket; i += blockDim.x) h[i] = 0;
    __syncthreads();
    int lo = blk * chunk, hi = min(lo + chunk, E);
    for (int e = lo + threadIdx.x; e < hi; e += blockDim.x)
        atomicAdd(&h[dst[e] >> 8], 1);
    __syncthreads();
    for (int i = threadIdx.x; i < nbucket; i += blockDim.x)
        cnt[i * NBLK + blk] = h[i];  // bucket-major, block-minor
}

__global__ void row_scan(int* __restrict__ cnt, int* __restrict__ totals) {
    __shared__ int lds[NBLK];
    int b = blockIdx.x, t = threadIdx.x;
    int v = cnt[b * NBLK + t];
    lds[t] = v;
    __syncthreads();
    for (int off = 1; off < NBLK; off <<= 1) {
        int y = (t >= off) ? lds[t - off] : 0;
        __syncthreads();
        lds[t] += y;
        __syncthreads();
    }
    cnt[b * NBLK + t] = lds[t] - v;
    if (t == NBLK - 1) totals[b] = lds[NBLK - 1];
}

__global__ void total_scan(int* __restrict__ totals, int nb) {
    __shared__ int lds[256];
    __shared__ int carry;
    int t = threadIdx.x;
    if (t == 0) carry = 0;
    __syncthreads();
    for (int c = 0; c < nb; c += 256) {
        int v = (c + t < nb) ? totals[c + t] : 0;
        lds[t] = v;
        __syncthreads();
        for (int off = 1; off < 256; off <<= 1) {
            int y = (t >= off) ? lds[t - off] : 0;
            __syncthreads();
            lds[t] += y;
            __syncthreads();
        }
        if (c + t < nb) totals[c + t] = carry + lds[t] - v;
        __syncthreads();
        if (t == 0) carry += lds[255];
        __syncthreads();
    }
    if (t == 0) totals[nb] = carry;
}

__global__ void pass_scatter(const int* __restrict__ src, const int* __restrict__ dst,
                             const int* __restrict__ cnt, const int* __restrict__ totals,
                             int* __restrict__ bucketed, int E, int nbucket, int chunk) {
    extern __shared__ int lcur[];
    int blk = blockIdx.x;
    for (int i = threadIdx.x; i < nbucket; i += blockDim.x)
        lcur[i] = cnt[i * NBLK + blk] + totals[i];
    __syncthreads();
    int lo = blk * chunk, hi = min(lo + chunk, E);
    for (int e = lo + threadIdx.x; e < hi; e += blockDim.x) {
        int s = src[e], d = dst[e];
        int pos = atomicAdd(&lcur[d >> 8], 1);
        bucketed[pos] = (s << 8) | (d & 255);
    }
}

__global__ void bucket_finalize(const int* __restrict__ bucketed, const int* __restrict__ totals,
                                int* __restrict__ rowptr, int* __restrict__ rowend,
                                float* __restrict__ dinv, int* __restrict__ csr_src, int n) {
    __shared__ int deg[256], sc[256], lcur[256];
    int b = blockIdx.x, t = threadIdx.x;
    int base = totals[b], bend = totals[b + 1];
    deg[t] = 0;
    __syncthreads();
    for (int i = base + t; i < bend; i += 256)
        atomicAdd(&deg[bucketed[i] & 255], 1);
    __syncthreads();
    int v = deg[t];
    sc[t] = v;
    __syncthreads();
    for (int off = 1; off < 256; off <<= 1) {
        int y = (t >= off) ? sc[t - off] : 0;
        __syncthreads();
        sc[t] += y;
        __syncthreads();
    }
    int ex = sc[t] - v;
    lcur[t] = ex;
    int node = b * 256 + t;
    if (node < n) {
        rowptr[node] = base + ex;
        rowend[node] = base + ex + v;
        dinv[node] = rsqrtf((float)(v + 1));
    }
    __syncthreads();
    for (int i = base + t; i < bend; i += 256) {
        int p = bucketed[i];
        int pos = atomicAdd(&lcur[p & 255], 1);
        csr_src[base + pos] = p >> 8;
    }
}

// ================= feature conversion =================

__global__ void to_bf16_words(const float* __restrict__ in, uint* __restrict__ outw,
                              long long nwords) {
    long long i = (long long)blockIdx.x * blockDim.x + threadIdx.x;
    if (i < nwords) {
        float2 v = reinterpret_cast<const float2*>(in)[i];
        outw[i] = pack_bf16(v.x, v.y);
    }
}

// ================= aggregation (gather, bf16 in, bf16 out) =================

template <int DW, int NPB>  // words per row; nodes per 256-thread block = 256/DW
__global__ void agg_gather_bf16(const int* __restrict__ rowptr, const int* __restrict__ rowend,
                                const int* __restrict__ csr_src, const float* __restrict__ dinv,
                                const uint* __restrict__ feat, uint* __restrict__ out, int n) {
    int node = blockIdx.x * NPB + (threadIdx.x / DW);
    int j = threadIdx.x % DW;
    if (node >= n) return;
    int k = rowptr[node];
    int end = rowend[node];
    float di = dinv[node];
    uint w = feat[(size_t)node * DW + j];
    float a0 = bf_lo(w) * di * di;
    float a1 = bf_hi(w) * di * di;
    for (; k + 4 <= end; k += 4) {
        int s0 = csr_src[k], s1 = csr_src[k + 1], s2 = csr_src[k + 2], s3 = csr_src[k + 3];
        float w0 = dinv[s0] * di, w1 = dinv[s1] * di, w2 = dinv[s2] * di, w3 = dinv[s3] * di;
        uint u0 = feat[(size_t)s0 * DW + j];
        uint u1 = feat[(size_t)s1 * DW + j];
        uint u2 = feat[(size_t)s2 * DW + j];
        uint u3 = feat[(size_t)s3 * DW + j];
        a0 += bf_lo(u0) * w0 + bf_lo(u1) * w1 + bf_lo(u2) * w2 + bf_lo(u3) * w3;
        a1 += bf_hi(u0) * w0 + bf_hi(u1) * w1 + bf_hi(u2) * w2 + bf_hi(u3) * w3;
    }
    for (; k < end; ++k) {
        int s = csr_src[k];
        float ws = dinv[s] * di;
        uint u = feat[(size_t)s * DW + j];
        a0 += bf_lo(u) * ws;
        a1 += bf_hi(u) * ws;
    }
    out[(size_t)node * DW + j] = pack_bf16(a0, a1);
}

// ================= MFMA dense layers =================
// Fragment layouts (gfx950 16x16x32 bf16, per verified m89 mapping):
//  A: lane l, elem j -> A[l&15][(l>>4)*8 + j]
//  B: lane l, elem j -> B[(l>>4)*8 + j][l&15]
//  D: lane l, reg  r -> D[(l>>4)*4 + r][l&15]

__device__ __forceinline__ short8 make_bfrag(const float* __restrict__ W, int kbase, int col) {
    uint w0 = pack_bf16(W[(kbase + 0) * 64 + col], W[(kbase + 1) * 64 + col]);
    uint w1 = pack_bf16(W[(kbase + 2) * 64 + col], W[(kbase + 3) * 64 + col]);
    uint w2 = pack_bf16(W[(kbase + 4) * 64 + col], W[(kbase + 5) * 64 + col]);
    uint w3 = pack_bf16(W[(kbase + 6) * 64 + col], W[(kbase + 7) * 64 + col]);
    uint4 u; u.x = w0; u.y = w1; u.z = w2; u.w = w3;
    return __builtin_bit_cast(short8, u);
}

// h1 = relu(A@W1 + b1), A [npad,16w] bf16 (K=32), out bf16 [npad,32w]
__global__ __launch_bounds__(256) void gemm1_mfma(const uint* __restrict__ A,
                                                  const float* __restrict__ W,
                                                  const float* __restrict__ bias,
                                                  uint* __restrict__ outw) {
    int t = threadIdx.x;
    int lane = t & 63, wv = t >> 6;
    int rowbase = blockIdx.x * 64 + wv * 16;
    int r16 = lane & 15, g4 = lane >> 4;
    short8 a = __builtin_bit_cast(short8,
        *reinterpret_cast<const uint4*>(A + (size_t)(rowbase + r16) * 16 + g4 * 4));
    int kbase = g4 * 8;
#pragma unroll
    for (int nt = 0; nt < 4; ++nt) {
        int col = nt * 16 + r16;
        short8 b = make_bfrag(W, kbase, col);
        f32x4 z = {0.f, 0.f, 0.f, 0.f};
        f32x4 acc = __builtin_amdgcn_mfma_f32_16x16x32_bf16(a, b, z, 0, 0, 0);
        float bcol = bias[col];
#pragma unroll
        for (int r = 0; r < 4; ++r) {
            int row = rowbase + g4 * 4 + r;
            float v = fmaxf(acc[r] + bcol, 0.f);
            float o = __shfl_xor(v, 1);
            if ((lane & 1) == 0)
                outw[(size_t)row * 32 + nt * 8 + (r16 >> 1)] = pack_bf16(v, o);
        }
    }
}

// pool[j] += sum_rows relu(A@W2 + b2), A [npad,32w] bf16 (K=64); h2 never stored
__global__ __launch_bounds__(256) void gemm2_mfma_pool(const uint* __restrict__ A,
                                                       const float* __restrict__ W,
                                                       const float* __restrict__ bias,
                                                       float* __restrict__ g, int n) {
    __shared__ float sblk[64];
    int t = threadIdx.x;
    if (t < 64) sblk[t] = 0.f;
    __syncthreads();
    int lane = t & 63, wv = t >> 6;
    int rowbase = blockIdx.x * 64 + wv * 16;
    int r16 = lane & 15, g4 = lane >> 4;
    const uint* arow = A + (size_t)(rowbase + r16) * 32 + g4 * 4;
    short8 a0 = __builtin_bit_cast(short8, *reinterpret_cast<const uint4*>(arow));
    short8 a1 = __builtin_bit_cast(short8, *reinterpret_cast<const uint4*>(arow + 16));
#pragma unroll
    for (int nt = 0; nt < 4; ++nt) {
        int col = nt * 16 + r16;
        short8 b0 = make_bfrag(W, g4 * 8, col);
        short8 b1 = make_bfrag(W, 32 + g4 * 8, col);
        f32x4 z = {0.f, 0.f, 0.f, 0.f};
        f32x4 acc = __builtin_amdgcn_mfma_f32_16x16x32_bf16(a0, b0, z, 0, 0, 0);
        acc = __builtin_amdgcn_mfma_f32_16x16x32_bf16(a1, b1, acc, 0, 0, 0);
        float bcol = bias[col];
        float part = 0.f;
#pragma unroll
        for (int r = 0; r < 4; ++r) {
            int row = rowbase + g4 * 4 + r;
            float v = fmaxf(acc[r] + bcol, 0.f);
            part += (row < n) ? v : 0.f;
        }
        atomicAdd(&sblk[col], part);
    }
    __syncthreads();
    if (t < 64) atomicAdd(&g[t], sblk[t]);
}

__global__ void final_head(const float* __restrict__ g, const float* __restrict__ Wfc,
                           const float* __restrict__ bfc, float* __restrict__ out, int n) {
    __shared__ float logits[5];
    int t = threadIdx.x;
    if (t < 5) {
        float acc = bfc[t];
        float invn = 1.0f / (float)n;
        for (int k = 0; k < 64; ++k) acc += (g[k] * invn) * Wfc[k * 5 + t];
        logits[t] = acc;
    }
    __syncthreads();
    if (t == 0) {
        float m = logits[0];
        for (int i = 1; i < 5; ++i) m = fmaxf(m, logits[i]);
        float s = 0.0f;
        for (int i = 0; i < 5; ++i) s += expf(logits[i] - m);
        float lse = m + logf(s);
        for (int i = 0; i < 5; ++i) out[i] = logits[i] - lse;
    }
}

// ================= launch =================

extern "C" void kernel_launch(void* const* d_in, const int* in_sizes, int n_in,
                              void* d_out, int out_size, void* d_ws, size_t ws_size,
                              hipStream_t stream) {
    const float* x   = (const float*)d_in[0];
    const int*   ei  = (const int*)d_in[1];
    const float* W1  = (const float*)d_in[2];
    const float* b1  = (const float*)d_in[3];
    const float* W2  = (const float*)d_in[4];
    const float* b2  = (const float*)d_in[5];
    const float* Wfc = (const float*)d_in[6];
    const float* bfc = (const float*)d_in[7];
    float* out = (float*)d_out;

    const int n = in_sizes[0] / 32;   // 100000
    const int E = in_sizes[1] / 2;    // 1600000
    const int* src = ei;
    const int* dst = ei + E;
    const int npad = (n + 63) & ~63;
    const int nbucket = (n + 255) >> 8;
    const int chunk = (E + NBLK - 1) / NBLK;

    // workspace carve-up (4-byte units)
    int*   csr_src = (int*)d_ws;                       // [E]
    int*   rowptr  = csr_src + E;                      // [n]
    int*   rowend  = rowptr + n;                       // [n]
    float* dinv    = (float*)(rowend + n);             // [n]
    int*   cnt     = (int*)(dinv + n);                 // [nbucket*NBLK]
    int*   totals  = cnt + (size_t)nbucket * NBLK;     // [nbucket+1]
    uint*  xbf     = (uint*)(totals + nbucket + 1);    // [n*16]
    uint*  agg1    = xbf + (size_t)n * 16;             // [npad*16]
    uint*  h1bf    = agg1 + (size_t)npad * 16;         // [npad*32]
    uint*  agg2    = h1bf + (size_t)npad * 32;         // [npad*32]
    float* g       = (float*)(agg2 + (size_t)npad * 32); // [64]
    int*   bucketed = (int*)agg1;                      // alias: [E] consumed pre-agg (npad*16 >= E)

    const int B = 256;
    const size_t lds_b = (size_t)nbucket * sizeof(int);

    // ---- build CSR + norms (no global atomics) ----
    pass_hist<<<NBLK, B, lds_b, stream>>>(dst, cnt, E, nbucket, chunk);
    row_scan<<<nbucket, NBLK, 0, stream>>>(cnt, totals);
    total_scan<<<1, B, 0, stream>>>(totals, nbucket);
    pass_scatter<<<NBLK, B, lds_b, stream>>>(src, dst, cnt, totals, bucketed, E, nbucket, chunk);
    bucket_finalize<<<nbucket, B, 0, stream>>>(bucketed, totals, rowptr, rowend, dinv, csr_src, n);

    // ---- x -> bf16 words ----
    {
        long long nwords = (long long)n * 16;
        to_bf16_words<<<(int)((nwords + B - 1) / B), B, 0, stream>>>(x, xbf, nwords);
    }

    // ---- layer 1: agg(xbf) -> agg1 bf16 [n,16w]; MFMA gemm+bias+relu -> h1bf [npad,32w]
    agg_gather_bf16<16, 16><<<(n + 15) / 16, B, 0, stream>>>(rowptr, rowend, csr_src, dinv,
                                                             xbf, agg1, n);
    gemm1_mfma<<<npad / 64, B, 0, stream>>>(agg1, W1, b1, h1bf);

    // ---- layer 2: agg(h1bf) -> agg2 bf16 [n,32w]; MFMA gemm+relu+pool -> g[64]
    agg_gather_bf16<32, 8><<<(n + 7) / 8, B, 0, stream>>>(rowptr, rowend, csr_src, dinv,
                                                          h1bf, agg2, n);
    hipMemsetAsync(g, 0, 64 * sizeof(float), stream);
    gemm2_mfma_pool<<<npad / 64, B, 0, stream>>>(agg2, W2, b2, g, n);

    // ---- head ----
    final_head<<<1, 64, 0, stream>>>(g, Wfc, bfc, out, n);
}

// Round 7
// 175.296 us; speedup vs baseline: 2.9888x; 1.0615x over previous
//
#include <hip/hip_runtime.h>
#include <math.h>

#define NBLK 256  // chunks/blocks for hist+scatter

typedef unsigned int uint;
typedef __attribute__((ext_vector_type(8))) short short8;
typedef __attribute__((ext_vector_type(4))) float f32x4;

__device__ __forceinline__ uint pack_bf16(float a, float b) {
    uint ua = __float_as_uint(a), ub = __float_as_uint(b);
    ua = (ua + 0x7fffu + ((ua >> 16) & 1u)) >> 16;
    ub = (ub + 0x7fffu + ((ub >> 16) & 1u)) >> 16;
    return ua | (ub << 16);
}
__device__ __forceinline__ float bf_lo(uint w) { return __uint_as_float(w << 16); }
__device__ __forceinline__ float bf_hi(uint w) { return __uint_as_float(w & 0xffff0000u); }

// ================= deterministic bucketed CSR build =================

__global__ void pass_hist(const int* __restrict__ dst, int* __restrict__ cnt,
                          int E, int nbucket, int chunk) {
    extern __shared__ int h[];
    int blk = blockIdx.x;
    for (int i = threadIdx.x; i < nbucket; i += blockDim.x) h[i] = 0;
    __syncthreads();
    int lo = blk * chunk, hi = min(lo + chunk, E);
    for (int e = lo + threadIdx.x; e < hi; e += blockDim.x)
        atomicAdd(&h[dst[e] >> 8], 1);
    __syncthreads();
    for (int i = threadIdx.x; i < nbucket; i += blockDim.x)
        cnt[i * NBLK + blk] = h[i];  // bucket-major, block-minor
}

__global__ void row_scan(int* __restrict__ cnt, int* __restrict__ totals) {
    __shared__ int lds[NBLK];
    int b = blockIdx.x, t = threadIdx.x;
    int v = cnt[b * NBLK + t];
    lds[t] = v;
    __syncthreads();
    for (int off = 1; off < NBLK; off <<= 1) {
        int y = (t >= off) ? lds[t - off] : 0;
        __syncthreads();
        lds[t] += y;
        __syncthreads();
    }
    cnt[b * NBLK + t] = lds[t] - v;
    if (t == NBLK - 1) totals[b] = lds[NBLK - 1];
}

__global__ void total_scan(int* __restrict__ totals, int nb) {
    __shared__ int lds[256];
    __shared__ int carry;
    int t = threadIdx.x;
    if (t == 0) carry = 0;
    __syncthreads();
    for (int c = 0; c < nb; c += 256) {
        int v = (c + t < nb) ? totals[c + t] : 0;
        lds[t] = v;
        __syncthreads();
        for (int off = 1; off < 256; off <<= 1) {
            int y = (t >= off) ? lds[t - off] : 0;
            __syncthreads();
            lds[t] += y;
            __syncthreads();
        }
        if (c + t < nb) totals[c + t] = carry + lds[t] - v;
        __syncthreads();
        if (t == 0) carry += lds[255];
        __syncthreads();
    }
    if (t == 0) totals[nb] = carry;
}

__global__ void pass_scatter(const int* __restrict__ src, const int* __restrict__ dst,
                             const int* __restrict__ cnt, const int* __restrict__ totals,
                             int* __restrict__ bucketed, int E, int nbucket, int chunk) {
    extern __shared__ int lcur[];
    int blk = blockIdx.x;
    for (int i = threadIdx.x; i < nbucket; i += blockDim.x)
        lcur[i] = cnt[i * NBLK + blk] + totals[i];
    __syncthreads();
    int lo = blk * chunk, hi = min(lo + chunk, E);
    for (int e = lo + threadIdx.x; e < hi; e += blockDim.x) {
        int s = src[e], d = dst[e];
        int pos = atomicAdd(&lcur[d >> 8], 1);
        bucketed[pos] = (s << 8) | (d & 255);
    }
}

__global__ void bucket_finalize(const int* __restrict__ bucketed, const int* __restrict__ totals,
                                int* __restrict__ rowptr, int* __restrict__ rowend,
                                float* __restrict__ dinv, int* __restrict__ csr_src, int n) {
    __shared__ int deg[256], sc[256], lcur[256];
    int b = blockIdx.x, t = threadIdx.x;
    int base = totals[b], bend = totals[b + 1];
    deg[t] = 0;
    __syncthreads();
    for (int i = base + t; i < bend; i += 256)
        atomicAdd(&deg[bucketed[i] & 255], 1);
    __syncthreads();
    int v = deg[t];
    sc[t] = v;
    __syncthreads();
    for (int off = 1; off < 256; off <<= 1) {
        int y = (t >= off) ? sc[t - off] : 0;
        __syncthreads();
        sc[t] += y;
        __syncthreads();
    }
    int ex = sc[t] - v;
    lcur[t] = ex;
    int node = b * 256 + t;
    if (node < n) {
        rowptr[node] = base + ex;
        rowend[node] = base + ex + v;
        dinv[node] = rsqrtf((float)(v + 1));
    }
    __syncthreads();
    for (int i = base + t; i < bend; i += 256) {
        int p = bucketed[i];
        int pos = atomicAdd(&lcur[p & 255], 1);
        csr_src[base + pos] = p >> 8;
    }
}

// ================= feature conversion (pre-scaled by dinv, sliced) =================
// x [n][32] f32 -> xsl[2][npad][8 words] bf16, xsl row = dinv[v]*x[v][s*16..s*16+16)

__global__ void convert_x_sliced(const float* __restrict__ x, const float* __restrict__ dinv,
                                 uint* __restrict__ xsl, int n, int npad) {
    int i = blockIdx.x * blockDim.x + threadIdx.x;  // i = v*2 + s
    if (i >= n * 2) return;
    int v = i >> 1, s = i & 1;
    float di = dinv[v];
    const float* xr = x + (size_t)v * 32 + s * 16;
    uint w[8];
#pragma unroll
    for (int q = 0; q < 8; ++q) w[q] = pack_bf16(xr[2 * q] * di, xr[2 * q + 1] * di);
    uint* o = xsl + ((size_t)s * npad + v) * 8;
    uint4 u0; u0.x = w[0]; u0.y = w[1]; u0.z = w[2]; u0.w = w[3];
    uint4 u1; u1.x = w[4]; u1.y = w[5]; u1.z = w[6]; u1.w = w[7];
    *reinterpret_cast<uint4*>(o) = u0;
    *reinterpret_cast<uint4*>(o + 4) = u1;
}

// ================= sliced aggregation gather =================
// feat' sliced [nsl][npad][8w]; out[d] = dinv[d]*(feat'[d] + sum feat'[src]).
// One block = 64 nodes x 1 slice; 4 threads/node, 2 words (8B) each.
// slice = bid & (nsl-1) rides bid%8->XCD round-robin so each XCD keeps one
// 3.2MB slice L2-resident.

template <int LOG_NSL>
__global__ __launch_bounds__(256) void agg_gather_sliced(
    const int* __restrict__ rowptr, const int* __restrict__ rowend,
    const int* __restrict__ csr_src, const float* __restrict__ dinv,
    const uint* __restrict__ feat, uint* __restrict__ out, int n, int npad) {
    int bid = blockIdx.x;
    int slice = bid & ((1 << LOG_NSL) - 1);
    int chunk = bid >> LOG_NSL;
    int node = chunk * 64 + (threadIdx.x >> 2);
    if (node >= n) return;
    int j = (threadIdx.x & 3) * 2;  // word offset within 8-word slice row
    const uint* fs = feat + (size_t)slice * npad * 8 + j;
    uint* os = out + (size_t)slice * npad * 8 + j;
    int k = rowptr[node], end = rowend[node];
    uint2 w = *reinterpret_cast<const uint2*>(fs + (size_t)node * 8);
    float a0 = bf_lo(w.x), a1 = bf_hi(w.x), a2 = bf_lo(w.y), a3 = bf_hi(w.y);
    for (; k + 4 <= end; k += 4) {
        int s0 = csr_src[k], s1 = csr_src[k + 1], s2 = csr_src[k + 2], s3 = csr_src[k + 3];
        uint2 u0 = *reinterpret_cast<const uint2*>(fs + (size_t)s0 * 8);
        uint2 u1 = *reinterpret_cast<const uint2*>(fs + (size_t)s1 * 8);
        uint2 u2 = *reinterpret_cast<const uint2*>(fs + (size_t)s2 * 8);
        uint2 u3 = *reinterpret_cast<const uint2*>(fs + (size_t)s3 * 8);
        a0 += (bf_lo(u0.x) + bf_lo(u1.x)) + (bf_lo(u2.x) + bf_lo(u3.x));
        a1 += (bf_hi(u0.x) + bf_hi(u1.x)) + (bf_hi(u2.x) + bf_hi(u3.x));
        a2 += (bf_lo(u0.y) + bf_lo(u1.y)) + (bf_lo(u2.y) + bf_lo(u3.y));
        a3 += (bf_hi(u0.y) + bf_hi(u1.y)) + (bf_hi(u2.y) + bf_hi(u3.y));
    }
    for (; k < end; ++k) {
        int s = csr_src[k];
        uint2 u = *reinterpret_cast<const uint2*>(fs + (size_t)s * 8);
        a0 += bf_lo(u.x); a1 += bf_hi(u.x); a2 += bf_lo(u.y); a3 += bf_hi(u.y);
    }
    float di = dinv[node];
    uint2 o;
    o.x = pack_bf16(a0 * di, a1 * di);
    o.y = pack_bf16(a2 * di, a3 * di);
    *reinterpret_cast<uint2*>(os + (size_t)node * 8) = o;
}

// ================= MFMA dense layers =================
// Fragment layouts (gfx950 16x16x32 bf16, verified m89 mapping):
//  A: lane l, elem j -> A[l&15][(l>>4)*8 + j]
//  B: lane l, elem j -> B[(l>>4)*8 + j][l&15]
//  D: lane l, reg  r -> D[(l>>4)*4 + r][l&15]

__device__ __forceinline__ short8 make_bfrag(const float* __restrict__ W, int kbase, int col) {
    uint w0 = pack_bf16(W[(kbase + 0) * 64 + col], W[(kbase + 1) * 64 + col]);
    uint w1 = pack_bf16(W[(kbase + 2) * 64 + col], W[(kbase + 3) * 64 + col]);
    uint w2 = pack_bf16(W[(kbase + 4) * 64 + col], W[(kbase + 5) * 64 + col]);
    uint w3 = pack_bf16(W[(kbase + 6) * 64 + col], W[(kbase + 7) * 64 + col]);
    uint4 u; u.x = w0; u.y = w1; u.z = w2; u.w = w3;
    return __builtin_bit_cast(short8, u);
}

// h1' = dinv*relu(A@W1 + b1); A sliced [2][npad][8w] (K=32); out sliced [4][npad][8w]
__global__ __launch_bounds__(256) void gemm1_mfma(const uint* __restrict__ A,
                                                  const float* __restrict__ W,
                                                  const float* __restrict__ bias,
                                                  const float* __restrict__ dinv,
                                                  uint* __restrict__ outw, int n, int npad) {
    int t = threadIdx.x;
    int lane = t & 63, wv = t >> 6;
    int rowbase = blockIdx.x * 64 + wv * 16;
    int r16 = lane & 15, g4 = lane >> 4;
    short8 a = __builtin_bit_cast(short8, *reinterpret_cast<const uint4*>(
        A + ((size_t)(g4 >> 1) * npad + rowbase + r16) * 8 + (g4 & 1) * 4));
    int kbase = g4 * 8;
    float dr[4];
#pragma unroll
    for (int r = 0; r < 4; ++r) {
        int row = rowbase + g4 * 4 + r;
        dr[r] = (row < n) ? dinv[row] : 0.f;
    }
#pragma unroll
    for (int nt = 0; nt < 4; ++nt) {
        int col = nt * 16 + r16;
        short8 b = make_bfrag(W, kbase, col);
        f32x4 z = {0.f, 0.f, 0.f, 0.f};
        f32x4 acc = __builtin_amdgcn_mfma_f32_16x16x32_bf16(a, b, z, 0, 0, 0);
        float bcol = bias[col];
#pragma unroll
        for (int r = 0; r < 4; ++r) {
            int row = rowbase + g4 * 4 + r;
            float v = fmaxf(acc[r] + bcol, 0.f) * dr[r];
            float o = __shfl_xor(v, 1);
            if ((lane & 1) == 0)
                outw[((size_t)nt * npad + row) * 8 + (r16 >> 1)] = pack_bf16(v, o);
        }
    }
}

// pool[j] += sum_rows relu(A@W2 + b2); A sliced [4][npad][8w] (K=64); h2 never stored
__global__ __launch_bounds__(256) void gemm2_mfma_pool(const uint* __restrict__ A,
                                                       const float* __restrict__ W,
                                                       const float* __restrict__ bias,
                                                       float* __restrict__ g, int n, int npad) {
    __shared__ float sblk[64];
    int t = threadIdx.x;
    if (t < 64) sblk[t] = 0.f;
    __syncthreads();
    int lane = t & 63, wv = t >> 6;
    int rowbase = blockIdx.x * 64 + wv * 16;
    int r16 = lane & 15, g4 = lane >> 4;
    size_t roff = (size_t)(rowbase + r16) * 8 + (g4 & 1) * 4;
    size_t sstride = (size_t)npad * 8;
    short8 a0 = __builtin_bit_cast(short8,
        *reinterpret_cast<const uint4*>(A + (size_t)(g4 >> 1) * sstride + roff));
    short8 a1 = __builtin_bit_cast(short8,
        *reinterpret_cast<const uint4*>(A + (size_t)(2 + (g4 >> 1)) * sstride + roff));
#pragma unroll
    for (int nt = 0; nt < 4; ++nt) {
        int col = nt * 16 + r16;
        short8 b0 = make_bfrag(W, g4 * 8, col);
        short8 b1 = make_bfrag(W, 32 + g4 * 8, col);
        f32x4 z = {0.f, 0.f, 0.f, 0.f};
        f32x4 acc = __builtin_amdgcn_mfma_f32_16x16x32_bf16(a0, b0, z, 0, 0, 0);
        acc = __builtin_amdgcn_mfma_f32_16x16x32_bf16(a1, b1, acc, 0, 0, 0);
        float bcol = bias[col];
        float part = 0.f;
#pragma unroll
        for (int r = 0; r < 4; ++r) {
            int row = rowbase + g4 * 4 + r;
            float v = fmaxf(acc[r] + bcol, 0.f);
            part += (row < n) ? v : 0.f;
        }
        atomicAdd(&sblk[col], part);
    }
    __syncthreads();
    if (t < 64) atomicAdd(&g[t], sblk[t]);
}

__global__ void final_head(const float* __restrict__ g, const float* __restrict__ Wfc,
                           const float* __restrict__ bfc, float* __restrict__ out, int n) {
    __shared__ float logits[5];
    int t = threadIdx.x;
    if (t < 5) {
        float acc = bfc[t];
        float invn = 1.0f / (float)n;
        for (int k = 0; k < 64; ++k) acc += (g[k] * invn) * Wfc[k * 5 + t];
        logits[t] = acc;
    }
    __syncthreads();
    if (t == 0) {
        float m = logits[0];
        for (int i = 1; i < 5; ++i) m = fmaxf(m, logits[i]);
        float s = 0.0f;
        for (int i = 0; i < 5; ++i) s += expf(logits[i] - m);
        float lse = m + logf(s);
        for (int i = 0; i < 5; ++i) out[i] = logits[i] - lse;
    }
}

// ================= launch =================

extern "C" void kernel_launch(void* const* d_in, const int* in_sizes, int n_in,
                              void* d_out, int out_size, void* d_ws, size_t ws_size,
                              hipStream_t stream) {
    const float* x   = (const float*)d_in[0];
    const int*   ei  = (const int*)d_in[1];
    const float* W1  = (const float*)d_in[2];
    const float* b1  = (const float*)d_in[3];
    const float* W2  = (const float*)d_in[4];
    const float* b2  = (const float*)d_in[5];
    const float* Wfc = (const float*)d_in[6];
    const float* bfc = (const float*)d_in[7];
    float* out = (float*)d_out;

    const int n = in_sizes[0] / 32;   // 100000
    const int E = in_sizes[1] / 2;    // 1600000
    const int* src = ei;
    const int* dst = ei + E;
    const int npad = (n + 63) & ~63;
    const int nbucket = (n + 255) >> 8;
    const int chunk = (E + NBLK - 1) / NBLK;
    const int nchunk = (n + 63) / 64;

    // workspace carve-up (4-byte units)
    int*   csr_src = (int*)d_ws;                        // [E]
    int*   rowptr  = csr_src + E;                       // [n]
    int*   rowend  = rowptr + n;                        // [n]
    float* dinv    = (float*)(rowend + n);              // [n]
    int*   cnt     = (int*)(dinv + n);                  // [nbucket*NBLK]
    int*   totals  = cnt + (size_t)nbucket * NBLK;      // [nbucket+1]
    uint*  xsl     = (uint*)(totals + nbucket + 1);     // [2*npad*8]
    uint*  agg1    = xsl + (size_t)2 * npad * 8;        // [2*npad*8]
    uint*  h1sl    = agg1 + (size_t)2 * npad * 8;       // [4*npad*8]
    uint*  agg2    = h1sl + (size_t)4 * npad * 8;       // [4*npad*8]
    float* g       = (float*)(agg2 + (size_t)4 * npad * 8); // [64]
    int*   bucketed = (int*)agg2;                       // alias: [E] consumed pre-agg (4*npad*8 >= E)

    const int B = 256;
    const size_t lds_b = (size_t)nbucket * sizeof(int);

    // ---- build CSR + norms (no global atomics) ----
    pass_hist<<<NBLK, B, lds_b, stream>>>(dst, cnt, E, nbucket, chunk);
    row_scan<<<nbucket, NBLK, 0, stream>>>(cnt, totals);
    total_scan<<<1, B, 0, stream>>>(totals, nbucket);
    pass_scatter<<<NBLK, B, lds_b, stream>>>(src, dst, cnt, totals, bucketed, E, nbucket, chunk);
    bucket_finalize<<<nbucket, B, 0, stream>>>(bucketed, totals, rowptr, rowend, dinv, csr_src, n);

    // ---- x -> pre-scaled sliced bf16 ----
    convert_x_sliced<<<(n * 2 + B - 1) / B, B, 0, stream>>>(x, dinv, xsl, n, npad);

    // ---- layer 1: sliced gather (2 slices) -> agg1; MFMA gemm -> h1' sliced [4] ----
    agg_gather_sliced<1><<<nchunk * 2, B, 0, stream>>>(rowptr, rowend, csr_src, dinv,
                                                       xsl, agg1, n, npad);
    gemm1_mfma<<<npad / 64, B, 0, stream>>>(agg1, W1, b1, dinv, h1sl, n, npad);

    // ---- layer 2: sliced gather (4 slices) -> agg2; MFMA gemm+relu+pool -> g ----
    agg_gather_sliced<2><<<nchunk * 4, B, 0, stream>>>(rowptr, rowend, csr_src, dinv,
                                                       h1sl, agg2, n, npad);
    hipMemsetAsync(g, 0, 64 * sizeof(float), stream);
    gemm2_mfma_pool<<<npad / 64, B, 0, stream>>>(agg2, W2, b2, g, n, npad);

    // ---- head ----
    final_head<<<1, 64, 0, stream>>>(g, Wfc, bfc, out, n);
}